// Round 2
// baseline (502.600 us; speedup 1.0000x reference)
//
#include <hip/hip_runtime.h>

#define NEGF (-1e30f)

// reduce across the 4 lanes of one matrix column (lanes 4m..4m+3)
__device__ __forceinline__ float colmax(float v) {
  v = fmaxf(v, __shfl_xor(v, 1));
  v = fmaxf(v, __shfl_xor(v, 2));
  return v;
}
__device__ __forceinline__ float colsum(float v) {
  v += __shfl_xor(v, 1);
  v += __shfl_xor(v, 2);
  return v;
}

struct Step {
  float beta[4], cont[4], es[4], al[4];
};

// Load one time-step's per-lane slice: rows k = 4r..4r+3.
// es[] = exp(start[]) precomputed here so it sits in the load shadow,
// off the per-step dependent chain.
__device__ __forceinline__ void load_step(
    const float* __restrict__ actl, const float* __restrict__ stopl,
    const float* __restrict__ startl, long bt /* batch*Tp1 + i */, int aidx,
    int A, int r, Step& s)
{
  const float4* sp = reinterpret_cast<const float4*>(stopl + bt * 32 + r * 8);
  float4 s0 = sp[0];
  float4 s1 = sp[1];
  s.beta[0] = s0.x; s.cont[0] = s0.y; s.beta[1] = s0.z; s.cont[1] = s0.w;
  s.beta[2] = s1.x; s.cont[2] = s1.y; s.beta[3] = s1.z; s.cont[3] = s1.w;
  float4 st = *reinterpret_cast<const float4*>(startl + bt * 16 + r * 4);
  s.es[0] = __expf(st.x); s.es[1] = __expf(st.y);
  s.es[2] = __expf(st.z); s.es[3] = __expf(st.w);
  const float* ap = actl + bt * (16L * A) + (long)(r * 4) * A + aidx;
  s.al[0] = ap[0];
  s.al[1] = ap[A];
  s.al[2] = ap[2 * A];
  s.al[3] = ap[3 * A];
}

// Kernel 1: one wave per (batch, chunk). Builds the 16x16 log-space transfer
// matrix for the chunk's time steps. Lane l: column m = l>>2, rows 4r..4r+3
// (r = l&3). Matrix kept column-normalized (Mn), per-column offset `off`.
//   S[m]     = lse_j(beta[j] + M[j,m])
//   M'[k,m]  = al[k] + logaddexp(start[k] + S[m], cont[k] + M[k,m])
// computed in the normalized frame as:
//   Mn'[k,m] = al[k] + log( s*exp(start[k]) + exp(cont[k] + Mn[k,m] - cmax) )
//   off     += cmax,  with s = sum_j exp(beta[j] + Mn[j,m] - cmax)
__global__ __launch_bounds__(256) void hmm_chunks(
    const float* __restrict__ action_logps,
    const float* __restrict__ stop_logps,
    const float* __restrict__ start_logps,
    const int* __restrict__ actions,
    const int* __restrict__ lengths,
    float* __restrict__ Mws, float* __restrict__ Offws,
    int B, int maxT, int A, int NC, int CHUNK)
{
  const int lane = threadIdx.x & 63;
  const int gw = blockIdx.x * (blockDim.x >> 6) + (threadIdx.x >> 6);
  if (gw >= B * NC) return;
  const int batch = gw / NC;
  const int chunk = gw % NC;
  const long Tp1 = (long)maxT + 1;
  const int m = lane >> 2;
  const int r = lane & 3;

  float M[4];
#pragma unroll
  for (int q = 0; q < 4; ++q) M[q] = (4 * r + q == m) ? 0.f : NEGF;
  float off = 0.f;

  const int len = lengths[batch];
  const int i0 = 1 + chunk * CHUNK;
  int i1 = i0 + CHUNK;
  if (i1 > maxT) i1 = maxT;     // reference scan runs i = 1 .. maxT-1
  if (i1 > len) i1 = len;       // mask: update only while i < length

  if (i0 < i1) {
    const int* actp = actions + (long)batch * maxT;
    const long bt0 = (long)batch * Tp1;
    const int n = i1 - i0;
    Step cur, n1, n2;
    load_step(action_logps, stop_logps, start_logps, bt0 + i0, actp[i0], A, r, cur);
    if (n > 1)
      load_step(action_logps, stop_logps, start_logps, bt0 + i0 + 1, actp[i0 + 1], A, r, n1);
    int a2 = (n > 2) ? actp[i0 + 2] : 0;   // action idx for step i+2
    int a3 = (n > 3) ? actp[i0 + 3] : 0;   // action idx for step i+3

    for (int i = i0; i < i1; ++i) {
      // issue loads 2 steps ahead
      if (i + 2 < i1)
        load_step(action_logps, stop_logps, start_logps, bt0 + i + 2, a2, A, r, n2);
      a2 = a3;
      a3 = (i + 4 < i1) ? actp[i + 4] : 0;

      // column max (normalization shift)
      float cmax = fmaxf(fmaxf(M[0], M[1]), fmaxf(M[2], M[3]));
      cmax = colmax(cmax);
      float Ms[4];
#pragma unroll
      for (int q = 0; q < 4; ++q) Ms[q] = M[q] - cmax;

      // s = sum_j exp(beta[j] + Mn[j,m] - cmax)
      float p = __expf(cur.beta[0] + Ms[0]) + __expf(cur.beta[1] + Ms[1]) +
                __expf(cur.beta[2] + Ms[2]) + __expf(cur.beta[3] + Ms[3]);
      const float ssum = colsum(p);

#pragma unroll
      for (int q = 0; q < 4; ++q) {
        const float e2 = __expf(cur.cont[q] + Ms[q]);
        M[q] = cur.al[q] + __logf(fmaxf(ssum * cur.es[q] + e2, 1e-37f));
      }
      off += cmax;

      cur = n1;
      n1 = n2;
    }
  }

  // store: Mws[gw][m][k] (column m contiguous over k) + off per column
  float4 mv = make_float4(M[0], M[1], M[2], M[3]);
  *reinterpret_cast<float4*>(Mws + (long)gw * 256 + (m * 16 + r * 4)) = mv;
  if (r == 0) Offws[(long)gw * 16 + m] = off;
}

// Kernel 2: one wave per batch. f'[k] = lse_j( M_c[k,j] + off_c[j] + f[j] ),
// chunks applied in order; chunk matrices past `length` are identity so no
// masking needed here. Lane l: k = l&15, j-group jg = l>>4 (4 j's per lane).
__global__ __launch_bounds__(256) void hmm_combine(
    const float* __restrict__ action_logps,
    const float* __restrict__ stop_logps,
    const float* __restrict__ start_logps,
    const int* __restrict__ actions,
    const int* __restrict__ lengths,
    const float* __restrict__ Mws, const float* __restrict__ Offws,
    float* __restrict__ out,
    int B, int maxT, int A, int NC)
{
  const int batch = blockIdx.x * (blockDim.x >> 6) + (threadIdx.x >> 6);
  if (batch >= B) return;
  const int lane = threadIdx.x & 63;
  const int k = lane & 15;
  const int jg = lane >> 4;
  const long Tp1 = (long)maxT + 1;

  // f0[k] = start[b,0,k] + action_logps[b,0,k,a0]
  const int a0 = actions[(long)batch * maxT];
  float f = start_logps[(long)batch * Tp1 * 16 + k] +
            action_logps[(long)batch * Tp1 * (16L * A) + (long)k * A + a0];

  const float* Mb = Mws + (long)batch * NC * 256;
  const float* Ob = Offws + (long)batch * NC * 16;

  constexpr int PF = 4;  // prefetch depth (NC is a multiple of 4 by host construction)
  float pm[PF][4], po[PF][4];
#pragma unroll
  for (int d = 0; d < PF; ++d) {
#pragma unroll
    for (int q = 0; q < 4; ++q) {
      pm[d][q] = Mb[d * 256 + (4 * jg + q) * 16 + k];
      po[d][q] = Ob[d * 16 + 4 * jg + q];
    }
  }

  for (int cb = 0; cb < NC; cb += PF) {
#pragma unroll
    for (int u = 0; u < PF; ++u) {
      const int c = cb + u;
      float v[4];
      float mx = NEGF;
#pragma unroll
      for (int q = 0; q < 4; ++q) {
        const float fj = __shfl(f, 4 * jg + q);  // lane j holds f[j]
        v[q] = pm[u][q] + po[u][q] + fj;
        mx = fmaxf(mx, v[q]);
      }
      mx = fmaxf(mx, __shfl_xor(mx, 16));
      mx = fmaxf(mx, __shfl_xor(mx, 32));
      float s = 0.f;
#pragma unroll
      for (int q = 0; q < 4; ++q) s += __expf(v[q] - mx);
      s += __shfl_xor(s, 16);
      s += __shfl_xor(s, 32);
      f = mx + __logf(s);

      const int cn = c + PF;
      if (cn < NC) {
#pragma unroll
        for (int q = 0; q < 4; ++q) {
          pm[u][q] = Mb[(long)cn * 256 + (4 * jg + q) * 16 + k];
          po[u][q] = Ob[cn * 16 + 4 * jg + q];
        }
      }
    }
  }

  // finalize: total = lse_k( f[k] + stop[b, L, k, STOP] ); out += -total
  const int L = lengths[batch];
  const float st = stop_logps[((long)batch * Tp1 + L) * 32 + k * 2];
  const float v = f + st;
  float mx = v;
  mx = fmaxf(mx, __shfl_xor(mx, 1));
  mx = fmaxf(mx, __shfl_xor(mx, 2));
  mx = fmaxf(mx, __shfl_xor(mx, 4));
  mx = fmaxf(mx, __shfl_xor(mx, 8));
  float s = __expf(v - mx);
  s += __shfl_xor(s, 1);
  s += __shfl_xor(s, 2);
  s += __shfl_xor(s, 4);
  s += __shfl_xor(s, 8);
  const float tot = mx + __logf(s);
  if (lane == 0) atomicAdd(out, -tot);
}

extern "C" void kernel_launch(void* const* d_in, const int* in_sizes, int n_in,
                              void* d_out, int out_size, void* d_ws, size_t ws_size,
                              hipStream_t stream) {
  const float* action_logps = (const float*)d_in[0];
  const float* stop_logps = (const float*)d_in[1];
  const float* start_logps = (const float*)d_in[2];
  const int* actions = (const int*)d_in[3];
  const int* lengths = (const int*)d_in[4];

  const int B = in_sizes[4];
  const int maxT = in_sizes[3] / B;                       // actions: (B, maxT)
  const long Tp1 = (long)maxT + 1;
  const int b = (int)((long)in_sizes[1] / ((long)B * Tp1 * 2));  // must be 16
  const int A = (int)((long)in_sizes[0] / ((long)B * Tp1 * b));  // 18
  (void)b;

  int NC = 128;                                           // chunks over time
  const size_t per_chunk = (size_t)B * (256 + 16) * sizeof(float);
  if ((size_t)NC * per_chunk > ws_size) {                 // adapt to workspace
    NC = (int)(ws_size / per_chunk) & ~3;
    if (NC < 4) NC = 4;
  }
  const int CHUNK = (maxT - 1 + NC - 1) / NC;

  float* Mws = (float*)d_ws;                              // [B][NC][16][16]
  float* Offws = Mws + (size_t)B * NC * 256;              // [B][NC][16]

  hipMemsetAsync(d_out, 0, (size_t)out_size * sizeof(float), stream);

  const int nwaves = B * NC;
  hmm_chunks<<<dim3((nwaves + 3) / 4), dim3(256), 0, stream>>>(
      action_logps, stop_logps, start_logps, actions, lengths,
      Mws, Offws, B, maxT, A, NC, CHUNK);
  hmm_combine<<<dim3((B + 3) / 4), dim3(256), 0, stream>>>(
      action_logps, stop_logps, start_logps, actions, lengths,
      Mws, Offws, (float*)d_out, B, maxT, A, NC);
}

// Round 3
// 474.444 us; speedup vs baseline: 1.0593x; 1.0593x over previous
//
#include <hip/hip_runtime.h>

#define NEGF (-1e30f)

constexpr int TILE = 16;                 // steps staged per pipeline phase
constexpr int SSTR = 52;                 // floats per step slot (48 data + 4 pad: 2-way-free writes)
constexpr int SUBSTR = TILE * SSTR + 4;  // 836 floats per sub region (+4: subs offset 4 banks)

// Kernel 1 (v3): one wave handles 4 consecutive chunks (same batch) in
// probability space. Lane l = 16*g + m: sub-problem g, owns full column m
// (P[16] in registers). Per step (data staged in LDS, exp'd once):
//   sb    = sum_j eb[j] * P[j]            (in-lane dot, no shuffles)
//   P'[k] = es[k]*sb + cb[k]*P[k]         (pure FMA)
//   off  += log(colmax); P /= colmax      (scale tracked per column)
// with eb = exp(beta_i + al_{i-1}), cb = exp(cont_i + al_{i-1}), es = exp(start_i)
// (al row-factor folded into the NEXT step; final pending al applied at store).
// Masked/tail steps staged as eb=0, cb=1, es=0 => exact no-op.
__global__ __launch_bounds__(256) void hmm_chunks(
    const float* __restrict__ actl, const float* __restrict__ stopl,
    const float* __restrict__ startl, const int* __restrict__ actions,
    const int* __restrict__ lengths, float* __restrict__ Mws,
    float* __restrict__ Offws, int B, int maxT, int A, int NC, int CHUNK)
{
  __shared__ float lds[4 * 4 * SUBSTR];  // [wave][sub][tile-slot] = 53504 B
  const int wib = threadIdx.x >> 6;
  const int lane = threadIdx.x & 63;
  const int g = lane >> 4;
  const int m = lane & 15;   // compute: column; staging: step-within-tile
  const int cpw = NC / 4;    // waves per batch
  const int w = blockIdx.x * 4 + wib;
  const int batch = w / cpw;
  if (batch >= B) return;
  const int chunk = (w % cpw) * 4 + g;
  const long Tp1 = (long)maxT + 1;
  const long bt0 = (long)batch * Tp1;
  const int len = lengths[batch];
  const int i0 = 1 + chunk * CHUNK;
  const int cap = min(maxT, len);
  const int i1 = min(i0 + CHUNK, cap);
  const int n = max(0, i1 - i0);
  const int nmax = __shfl(n, 0);  // chunk idx lowest in lane 0..15 -> largest n
  float* ldsW = lds + wib * (4 * SUBSTR);

  float P[16];
#pragma unroll
  for (int k = 0; k < 16; ++k) P[k] = (k == m) ? 1.f : 0.f;
  float off = 0.f;

  if (nmax > 0) {
    const int ntiles = (nmax + TILE - 1) / TILE;
    const int* actp = actions + (long)batch * maxT;

    // staging register buffers (lane stages step i0 + tile*16 + m of sub g)
    float stv[32], srv[16], alp[16];
    bool pred = false;

    auto ld = [&](int tile) {
      const int s = tile * TILE + m;
      const int i = i0 + s;
      pred = (s < n);
      if (pred) {
        const float4* sv = reinterpret_cast<const float4*>(stopl + (bt0 + i) * 32);
#pragma unroll
        for (int q = 0; q < 8; ++q) {
          float4 v = sv[q];
          stv[4 * q] = v.x; stv[4 * q + 1] = v.y;
          stv[4 * q + 2] = v.z; stv[4 * q + 3] = v.w;
        }
        const float4* rv = reinterpret_cast<const float4*>(startl + (bt0 + i) * 16);
#pragma unroll
        for (int q = 0; q < 4; ++q) {
          float4 v = rv[q];
          srv[4 * q] = v.x; srv[4 * q + 1] = v.y;
          srv[4 * q + 2] = v.z; srv[4 * q + 3] = v.w;
        }
        if (s > 0) {
          const int ap = actp[i - 1];
          const float* ab = actl + (bt0 + i - 1) * (16L * A) + ap;
#pragma unroll
          for (int k = 0; k < 16; ++k) alp[k] = ab[(long)k * A];
        } else {
#pragma unroll
          for (int k = 0; k < 16; ++k) alp[k] = 0.f;
        }
      }
    };

    auto commit = [&]() {
      float* dst = ldsW + g * SUBSTR + m * SSTR;
      float ebv[16], cbv[16], esv[16];
      if (pred) {
#pragma unroll
        for (int k = 0; k < 16; ++k) {
          ebv[k] = __expf(stv[2 * k] + alp[k]);
          cbv[k] = __expf(stv[2 * k + 1] + alp[k]);
          esv[k] = __expf(srv[k]);
        }
      } else {
#pragma unroll
        for (int k = 0; k < 16; ++k) { ebv[k] = 0.f; cbv[k] = 1.f; esv[k] = 0.f; }
      }
      float4* d4 = reinterpret_cast<float4*>(dst);
#pragma unroll
      for (int q = 0; q < 4; ++q) {
        d4[q] = make_float4(ebv[4 * q], ebv[4 * q + 1], ebv[4 * q + 2], ebv[4 * q + 3]);
        d4[4 + q] = make_float4(cbv[4 * q], cbv[4 * q + 1], cbv[4 * q + 2], cbv[4 * q + 3]);
        d4[8 + q] = make_float4(esv[4 * q], esv[4 * q + 1], esv[4 * q + 2], esv[4 * q + 3]);
      }
    };

    auto compute_tile = [&]() {
      const float* src = ldsW + g * SUBSTR;
#pragma unroll 4
      for (int ss = 0; ss < TILE; ++ss) {
        const float4* l4 = reinterpret_cast<const float4*>(src + ss * SSTR);
        const float4 e0 = l4[0], e1 = l4[1], e2 = l4[2], e3 = l4[3];
        const float4 c0 = l4[4], c1 = l4[5], c2 = l4[6], c3 = l4[7];
        const float4 x0 = l4[8], x1 = l4[9], x2 = l4[10], x3 = l4[11];
        float sb = e0.x * P[0] + e0.y * P[1] + e0.z * P[2] + e0.w * P[3]
                 + e1.x * P[4] + e1.y * P[5] + e1.z * P[6] + e1.w * P[7]
                 + e2.x * P[8] + e2.y * P[9] + e2.z * P[10] + e2.w * P[11]
                 + e3.x * P[12] + e3.y * P[13] + e3.z * P[14] + e3.w * P[15];
        P[0] = x0.x * sb + c0.x * P[0];   P[1] = x0.y * sb + c0.y * P[1];
        P[2] = x0.z * sb + c0.z * P[2];   P[3] = x0.w * sb + c0.w * P[3];
        P[4] = x1.x * sb + c1.x * P[4];   P[5] = x1.y * sb + c1.y * P[5];
        P[6] = x1.z * sb + c1.z * P[6];   P[7] = x1.w * sb + c1.w * P[7];
        P[8] = x2.x * sb + c2.x * P[8];   P[9] = x2.y * sb + c2.y * P[9];
        P[10] = x2.z * sb + c2.z * P[10]; P[11] = x2.w * sb + c2.w * P[11];
        P[12] = x3.x * sb + c3.x * P[12]; P[13] = x3.y * sb + c3.y * P[13];
        P[14] = x3.z * sb + c3.z * P[14]; P[15] = x3.w * sb + c3.w * P[15];
        float c01 = fmaxf(P[0], P[1]),   c23 = fmaxf(P[2], P[3]);
        float c45 = fmaxf(P[4], P[5]),   c67 = fmaxf(P[6], P[7]);
        float c89 = fmaxf(P[8], P[9]),   cab = fmaxf(P[10], P[11]);
        float ccd = fmaxf(P[12], P[13]), cef = fmaxf(P[14], P[15]);
        float q0 = fmaxf(c01, c23), q1 = fmaxf(c45, c67);
        float q2 = fmaxf(c89, cab), q3 = fmaxf(ccd, cef);
        float cmax = fmaxf(fmaxf(q0, q1), fmaxf(q2, q3));
        cmax = fmaxf(cmax, 1e-30f);
        const float r = __builtin_amdgcn_rcpf(cmax);
        off += __logf(cmax);
#pragma unroll
        for (int k = 0; k < 16; ++k) P[k] *= r;
      }
    };

    ld(0);
    commit();
    if (ntiles > 1) ld(1);
    for (int t = 0; t < ntiles; ++t) {
      compute_tile();
      if (t + 1 < ntiles) {
        commit();
        if (t + 2 < ntiles) ld(t + 2);
      }
    }
  }

  // finale: apply pending al row-factor, convert to log, store M + off
  float pal[16];
  if (n > 0) {
    const int alast = actions[(long)batch * maxT + (i1 - 1)];
    const float* ab = actl + (bt0 + i1 - 1) * (16L * A) + alast;
#pragma unroll
    for (int k = 0; k < 16; ++k) pal[k] = ab[(long)k * A];
  } else {
#pragma unroll
    for (int k = 0; k < 16; ++k) pal[k] = 0.f;
  }
  float o[16];
#pragma unroll
  for (int k = 0; k < 16; ++k) {
    if (n > 0)
      o[k] = __logf(fmaxf(P[k], 1e-37f)) + pal[k];
    else
      o[k] = (k == m) ? 0.f : NEGF;
  }
  const long gw = (long)batch * NC + chunk;
  float4* mv = reinterpret_cast<float4*>(Mws + gw * 256 + m * 16);
  mv[0] = make_float4(o[0], o[1], o[2], o[3]);
  mv[1] = make_float4(o[4], o[5], o[6], o[7]);
  mv[2] = make_float4(o[8], o[9], o[10], o[11]);
  mv[3] = make_float4(o[12], o[13], o[14], o[15]);
  Offws[gw * 16 + m] = off;
}

// Kernel 2: one wave per batch. f'[k] = lse_j( M_c[k,j] + off_c[j] + f[j] ),
// chunks applied in order; chunk matrices past `length` are identity.
__global__ __launch_bounds__(256) void hmm_combine(
    const float* __restrict__ action_logps,
    const float* __restrict__ stop_logps,
    const float* __restrict__ start_logps,
    const int* __restrict__ actions,
    const int* __restrict__ lengths,
    const float* __restrict__ Mws, const float* __restrict__ Offws,
    float* __restrict__ out,
    int B, int maxT, int A, int NC)
{
  const int batch = blockIdx.x * (blockDim.x >> 6) + (threadIdx.x >> 6);
  if (batch >= B) return;
  const int lane = threadIdx.x & 63;
  const int k = lane & 15;
  const int jg = lane >> 4;
  const long Tp1 = (long)maxT + 1;

  const int a0 = actions[(long)batch * maxT];
  float f = start_logps[(long)batch * Tp1 * 16 + k] +
            action_logps[(long)batch * Tp1 * (16L * A) + (long)k * A + a0];

  const float* Mb = Mws + (long)batch * NC * 256;
  const float* Ob = Offws + (long)batch * NC * 16;

  constexpr int PF = 4;  // NC is a multiple of 4 by host construction
  float pm[PF][4], po[PF][4];
#pragma unroll
  for (int d = 0; d < PF; ++d) {
#pragma unroll
    for (int q = 0; q < 4; ++q) {
      pm[d][q] = Mb[d * 256 + (4 * jg + q) * 16 + k];
      po[d][q] = Ob[d * 16 + 4 * jg + q];
    }
  }

  for (int cb = 0; cb < NC; cb += PF) {
#pragma unroll
    for (int u = 0; u < PF; ++u) {
      const int c = cb + u;
      float v[4];
      float mx = NEGF;
#pragma unroll
      for (int q = 0; q < 4; ++q) {
        const float fj = __shfl(f, 4 * jg + q);
        v[q] = pm[u][q] + po[u][q] + fj;
        mx = fmaxf(mx, v[q]);
      }
      mx = fmaxf(mx, __shfl_xor(mx, 16));
      mx = fmaxf(mx, __shfl_xor(mx, 32));
      float s = 0.f;
#pragma unroll
      for (int q = 0; q < 4; ++q) s += __expf(v[q] - mx);
      s += __shfl_xor(s, 16);
      s += __shfl_xor(s, 32);
      f = mx + __logf(s);

      const int cn = c + PF;
      if (cn < NC) {
#pragma unroll
        for (int q = 0; q < 4; ++q) {
          pm[u][q] = Mb[(long)cn * 256 + (4 * jg + q) * 16 + k];
          po[u][q] = Ob[cn * 16 + 4 * jg + q];
        }
      }
    }
  }

  const int L = lengths[batch];
  const float st = stop_logps[((long)batch * Tp1 + L) * 32 + k * 2];
  const float v = f + st;
  float mx = v;
  mx = fmaxf(mx, __shfl_xor(mx, 1));
  mx = fmaxf(mx, __shfl_xor(mx, 2));
  mx = fmaxf(mx, __shfl_xor(mx, 4));
  mx = fmaxf(mx, __shfl_xor(mx, 8));
  float s = __expf(v - mx);
  s += __shfl_xor(s, 1);
  s += __shfl_xor(s, 2);
  s += __shfl_xor(s, 4);
  s += __shfl_xor(s, 8);
  const float tot = mx + __logf(s);
  if (lane == 0) atomicAdd(out, -tot);
}

extern "C" void kernel_launch(void* const* d_in, const int* in_sizes, int n_in,
                              void* d_out, int out_size, void* d_ws, size_t ws_size,
                              hipStream_t stream) {
  const float* action_logps = (const float*)d_in[0];
  const float* stop_logps = (const float*)d_in[1];
  const float* start_logps = (const float*)d_in[2];
  const int* actions = (const int*)d_in[3];
  const int* lengths = (const int*)d_in[4];

  const int B = in_sizes[4];
  const int maxT = in_sizes[3] / B;                       // actions: (B, maxT)
  const long Tp1 = (long)maxT + 1;
  const int b = (int)((long)in_sizes[1] / ((long)B * Tp1 * 2));  // 16
  const int A = (int)((long)in_sizes[0] / ((long)B * Tp1 * b));  // 18
  (void)b;

  int NC = 128;                                           // chunks over time
  const size_t per_chunk = (size_t)B * (256 + 16) * sizeof(float);
  if ((size_t)NC * per_chunk > ws_size) {
    NC = (int)(ws_size / per_chunk) & ~3;
    if (NC < 4) NC = 4;
  }
  const int CHUNK = (maxT - 1 + NC - 1) / NC;

  float* Mws = (float*)d_ws;                              // [B][NC][16][16]
  float* Offws = Mws + (size_t)B * NC * 256;              // [B][NC][16]

  hipMemsetAsync(d_out, 0, (size_t)out_size * sizeof(float), stream);

  const int nwaves = B * (NC / 4);                        // 4 chunks per wave
  hmm_chunks<<<dim3((nwaves + 3) / 4), dim3(256), 0, stream>>>(
      action_logps, stop_logps, start_logps, actions, lengths,
      Mws, Offws, B, maxT, A, NC, CHUNK);
  hmm_combine<<<dim3((B + 3) / 4), dim3(256), 0, stream>>>(
      action_logps, stop_logps, start_logps, actions, lengths,
      Mws, Offws, (float*)d_out, B, maxT, A, NC);
}